// Round 2
// baseline (547.634 us; speedup 1.0000x reference)
//
#include <hip/hip_runtime.h>
#include <math.h>
#include <float.h>

#define N_BATCH 256
#define C_IN    3
#define D_IN    32
#define HW_IN   32
#define C_OUT   24
#define KS      3
#define D_OUTS  30
#define HW_OUT  30
#define TH      8      // output h-rows per block
#define ROWS    10     // staged h-rows per slice (TH + 2 halo)
#define SLICE   (C_IN * ROWS * 32)   // floats per depth slice = 960

// Transpose weights (C_OUT,C_IN,K,K,K) -> wt[tap][c], tap=((ci*3+kd)*3+kh)*3+kw.
// Inner c-loop then reads 24 consecutive wave-uniform dwords -> s_load_dwordx8.
__global__ void prep_weights(const float* __restrict__ w, float* __restrict__ wt) {
    int i = blockIdx.x * blockDim.x + threadIdx.x;  // over 81*24
    if (i < 81 * C_OUT) {
        int tap = i / C_OUT;
        int c   = i - tap * C_OUT;
        wt[i] = w[c * 81 + tap];
    }
}

__global__ __launch_bounds__(256, 4) void conv3d_min_softmax(
    const float* __restrict__ x, const float* __restrict__ wt,
    const float* __restrict__ bias, float* __restrict__ out)
{
    // 3-deep ring of input depth slices, flat: phase p at [p*SLICE .. +SLICE)
    __shared__ float lds[3 * SLICE];

    const int tid = threadIdx.x;
    const int w   = tid & 31;          // output w lane (active if < 30)
    const int ty  = tid >> 5;          // output h row within tile
    const int n   = blockIdx.x >> 2;
    const int ht  = blockIdx.x & 3;
    const int h0  = ht * TH;
    const int h   = h0 + ty;
    const bool active = (w < HW_OUT) && (h < HW_OUT);
    const int vb = ty * 32 + w;        // per-thread element offset within a slice

    // Stage depth slice d (3 ci x up-to-10 rows x 32 w) into ring phase d%3.
    auto stage = [&](int d) {
        if (tid < 240) {
            int ci  = tid / 80;
            int rem = tid - ci * 80;
            int row = rem >> 3;
            int c4  = rem & 7;
            int gh  = h0 + row;
            if (gh < HW_IN) {
                const float4 v = *reinterpret_cast<const float4*>(
                    &x[(((size_t)(n * C_IN + ci) * D_IN + d) * HW_IN + gh) * HW_IN + c4 * 4]);
                *reinterpret_cast<float4*>(
                    &lds[(d % 3) * SLICE + (ci * ROWS + row) * 32 + c4 * 4]) = v;
            }
        }
    };

    float mn[C_OUT];
#pragma unroll
    for (int c = 0; c < C_OUT; ++c) mn[c] = FLT_MAX;

    stage(0);
    stage(1);

    // SGPR base-offset rotation instead of %3: pb0/pb1/pb2 = element offsets
    // of the slices for kd = 0,1,2 at the current output depth.
    int pb0 = 0, pb1 = SLICE, pb2 = 2 * SLICE;

    for (int dd = 0; dd < D_OUTS; ++dd) {
        stage(dd + 2);
        __syncthreads();
        if (active) {
            float acc[C_OUT];
#pragma unroll
            for (int c = 0; c < C_OUT; ++c) acc[c] = 0.f;
#pragma unroll
            for (int kd = 0; kd < KS; ++kd) {
                const int pb = (kd == 0) ? pb0 : (kd == 1) ? pb1 : pb2;
#pragma unroll
                for (int ci = 0; ci < C_IN; ++ci) {
#pragma unroll
                    for (int kh = 0; kh < KS; ++kh) {
#pragma unroll
                        for (int kw = 0; kw < KS; ++kw) {
                            // compile-time offset off (pb + vb): ds_read_b32 offset:N
                            const float xv =
                                lds[pb + vb + ci * (ROWS * 32) + kh * 32 + kw];
                            const int tap = ((ci * 3 + kd) * 3 + kh) * 3 + kw;
#pragma unroll
                            for (int c = 0; c < C_OUT; ++c)
                                acc[c] = fmaf(wt[tap * C_OUT + c], xv, acc[c]);
                        }
                    }
                }
            }
#pragma unroll
            for (int c = 0; c < C_OUT; ++c) mn[c] = fminf(mn[c], acc[c]);
        }
        __syncthreads();
        int t = pb0; pb0 = pb1; pb1 = pb2; pb2 = t;
    }

    if (active) {
        float v[C_OUT];
#pragma unroll
        for (int c = 0; c < C_OUT; ++c) v[c] = mn[c] + bias[c];  // bias commutes with min_d
        float m = v[0];
#pragma unroll
        for (int c = 1; c < C_OUT; ++c) m = fmaxf(m, v[c]);
        float s = 0.f;
#pragma unroll
        for (int c = 0; c < C_OUT; ++c) { v[c] = expf(v[c] - m); s += v[c]; }
        const float inv = 1.0f / s;
#pragma unroll
        for (int c = 0; c < C_OUT; ++c)
            out[((size_t)(n * C_OUT + c) * HW_OUT + h) * HW_OUT + w] = v[c] * inv;
    }
}

extern "C" void kernel_launch(void* const* d_in, const int* in_sizes, int n_in,
                              void* d_out, int out_size, void* d_ws, size_t ws_size,
                              hipStream_t stream) {
    const float* x    = (const float*)d_in[0];
    const float* wgt  = (const float*)d_in[1];
    const float* bias = (const float*)d_in[2];
    float* out = (float*)d_out;
    float* wt  = (float*)d_ws;   // 81*24*4 = 7776 bytes of scratch

    prep_weights<<<dim3((81 * C_OUT + 255) / 256), 256, 0, stream>>>(wgt, wt);
    conv3d_min_softmax<<<dim3(N_BATCH * 4), 256, 0, stream>>>(x, wt, bias, out);
}

// Round 3
// 337.738 us; speedup vs baseline: 1.6215x; 1.6215x over previous
//
#include <hip/hip_runtime.h>
#include <math.h>
#include <float.h>

typedef float v2f __attribute__((ext_vector_type(2)));

#define N_BATCH 256
#define C_IN    3
#define D_IN    32
#define HW_IN   32
#define C_OUT   24
#define NPAIR   12     // channel pairs -> v_pk_fma_f32
#define KS      3
#define D_OUTS  30
#define HW_OUT  30
#define TH      8      // output h-rows per block
#define ROWS    10     // staged h-rows per slice (TH + 2 halo)
#define SLICE   (C_IN * ROWS * 32)   // 960 floats per depth slice
#define NSLOT   4      // LDS ring depth (3 live + 1 staging)

// Transpose weights (C_OUT,C_IN,K,K,K) -> wt[tap][c], tap=((ci*3+kd)*3+kh)*3+kw.
// Channel pairs (c=2j,2j+1) are then contiguous 8B -> v2f weight operands.
__global__ void prep_weights(const float* __restrict__ w, float* __restrict__ wt) {
    int i = blockIdx.x * blockDim.x + threadIdx.x;  // over 81*24
    if (i < 81 * C_OUT) {
        int tap = i / C_OUT;
        int c   = i - tap * C_OUT;
        wt[i] = w[c * 81 + tap];
    }
}

static __device__ __forceinline__ v2f fma2(v2f a, float b, v2f c) {
#if __has_builtin(__builtin_elementwise_fma)
    v2f bb = {b, b};
    return __builtin_elementwise_fma(a, bb, c);   // -> v_pk_fma_f32
#else
    v2f r; r.x = fmaf(a.x, b, c.x); r.y = fmaf(a.y, b, c.y); return r;
#endif
}

static __device__ __forceinline__ v2f min2(v2f a, v2f b) {
#if __has_builtin(__builtin_elementwise_min)
    return __builtin_elementwise_min(a, b);
#else
    v2f r; r.x = fminf(a.x, b.x); r.y = fminf(a.y, b.y); return r;
#endif
}

__global__ __launch_bounds__(256) void conv3d_min_softmax(
    const float* __restrict__ x, const float* __restrict__ wt_,
    const float* __restrict__ bias, float* __restrict__ out)
{
    __shared__ __align__(16) float lds[NSLOT * SLICE];
    const v2f* __restrict__ wt2 = (const v2f*)wt_;

    const int tid = threadIdx.x;
    const int w   = tid & 31;          // output w lane (active if < 30)
    const int ty  = tid >> 5;          // output h row within tile
    const int n   = blockIdx.x >> 2;
    const int h0  = (blockIdx.x & 3) * TH;
    const int h   = h0 + ty;
    const bool active = (w < HW_OUT) && (h < HW_OUT);
    const int vb = ty * 32 + w;        // per-thread element offset within a slice

    // Staging mapping: 240 threads each move one float4 per depth slice.
    const int  sci  = tid / 80;                        // ci
    const int  srem = tid - sci * 80;
    const int  srow = srem >> 3;                       // h row 0..9
    const int  sc4  = (srem & 7) * 4;                  // w start
    const bool sth  = (tid < 240) && (h0 + srow < HW_IN);
    const size_t sgbase =
        ((size_t)(n * C_IN + sci) * D_IN) * (HW_IN * HW_IN)
        + (size_t)(h0 + srow) * HW_IN + sc4;           // + d*1024 per slice
    const int sldst = (sci * ROWS + srow) * 32 + sc4;  // LDS offset within slot

    auto load_slice = [&](int d) -> float4 {           // VMEM issue only
        float4 v = make_float4(0.f, 0.f, 0.f, 0.f);
        if (sth && d < D_IN)
            v = *reinterpret_cast<const float4*>(&x[sgbase + (size_t)d * (HW_IN * HW_IN)]);
        return v;
    };
    auto write_slice = [&](float* base, float4 v, int d) {
        if (sth && d < D_IN)
            *reinterpret_cast<float4*>(&base[sldst]) = v;
    };

    // Prologue: fill slots 0,1,2 with slices 0,1,2.
    {
        float4 s0 = load_slice(0), s1 = load_slice(1), s2 = load_slice(2);
        write_slice(&lds[0 * SLICE], s0, 0);
        write_slice(&lds[1 * SLICE], s1, 1);
        write_slice(&lds[2 * SLICE], s2, 2);
    }

    v2f mn[NPAIR];
#pragma unroll
    for (int j = 0; j < NPAIR; ++j) mn[j] = (v2f){FLT_MAX, FLT_MAX};

    const float* pA = &lds[0 * SLICE];   // slice dd   (kd=0)
    const float* pB = &lds[1 * SLICE];   // slice dd+1 (kd=1)
    const float* pC = &lds[2 * SLICE];   // slice dd+2 (kd=2)
    float*       pD = &lds[3 * SLICE];   // staging target (slice dd+3)

#define PHASE(P, KD)                                                          \
    do {                                                                      \
        const float* pp = (P) + vb;                                           \
        _Pragma("unroll")                                                     \
        for (int ci = 0; ci < C_IN; ++ci) {                                   \
            _Pragma("unroll")                                                 \
            for (int kh = 0; kh < KS; ++kh) {                                 \
                const float* pr = pp + ci * (ROWS * 32) + kh * 32;            \
                const float x0 = pr[0], x1 = pr[1], x2 = pr[2];               \
                const v2f* wp = wt2 + (((ci * 3 + (KD)) * 3 + kh) * 3) * NPAIR; \
                _Pragma("unroll")                                             \
                for (int j = 0; j < NPAIR; ++j) acc[j] = fma2(wp[j], x0, acc[j]); \
                _Pragma("unroll")                                             \
                for (int j = 0; j < NPAIR; ++j) acc[j] = fma2(wp[NPAIR + j], x1, acc[j]); \
                _Pragma("unroll")                                             \
                for (int j = 0; j < NPAIR; ++j) acc[j] = fma2(wp[2 * NPAIR + j], x2, acc[j]); \
            }                                                                 \
        }                                                                     \
    } while (0)

    for (int dd = 0; dd < D_OUTS; ++dd) {
        float4 nx = load_slice(dd + 3);      // issue early; completes under compute
        __syncthreads();                     // prev iter's ds_write visible; slot reads done
        if (active) {
            v2f acc[NPAIR];
#pragma unroll
            for (int j = 0; j < NPAIR; ++j) acc[j] = (v2f){0.f, 0.f};
            PHASE(pA, 0);
            PHASE(pB, 1);
            PHASE(pC, 2);
#pragma unroll
            for (int j = 0; j < NPAIR; ++j) mn[j] = min2(mn[j], acc[j]);
        }
        write_slice(pD, nx, dd + 3);         // writes slot read 2 iters ago — disjoint
        // rotate ring: next iter kd windows shift by one slice
        const float* t = pA;
        pA = pB; pB = pC; pC = pD; pD = (float*)t;
    }

    if (active) {
        float v[C_OUT];
#pragma unroll
        for (int j = 0; j < NPAIR; ++j) {    // bias commutes with min over depth
            v[2 * j]     = mn[j].x + bias[2 * j];
            v[2 * j + 1] = mn[j].y + bias[2 * j + 1];
        }
        float m = v[0];
#pragma unroll
        for (int c = 1; c < C_OUT; ++c) m = fmaxf(m, v[c]);
        float s = 0.f;
#pragma unroll
        for (int c = 0; c < C_OUT; ++c) { v[c] = expf(v[c] - m); s += v[c]; }
        const float inv = 1.0f / s;
#pragma unroll
        for (int c = 0; c < C_OUT; ++c)
            out[((size_t)(n * C_OUT + c) * HW_OUT + h) * HW_OUT + w] = v[c] * inv;
    }
}

extern "C" void kernel_launch(void* const* d_in, const int* in_sizes, int n_in,
                              void* d_out, int out_size, void* d_ws, size_t ws_size,
                              hipStream_t stream) {
    const float* x    = (const float*)d_in[0];
    const float* wgt  = (const float*)d_in[1];
    const float* bias = (const float*)d_in[2];
    float* out = (float*)d_out;
    float* wt  = (float*)d_ws;   // 81*24*4 = 7776 bytes of scratch

    prep_weights<<<dim3((81 * C_OUT + 255) / 256), 256, 0, stream>>>(wgt, wt);
    conv3d_min_softmax<<<dim3(N_BATCH * 4), 256, 0, stream>>>(x, wt, bias, out);
}

// Round 4
// 310.955 us; speedup vs baseline: 1.7611x; 1.0861x over previous
//
#include <hip/hip_runtime.h>
#include <math.h>
#include <float.h>

typedef float v2f __attribute__((ext_vector_type(2)));

#define N_BATCH 256
#define C_IN    3
#define D_IN    32
#define HW_IN   32
#define C_OUT   24
#define NPAIR   12     // channel pairs -> v_pk_fma_f32
#define D_OUTS  30
#define HW_OUT  30
#define TH      8      // output h-rows per block
#define ROWS    10     // staged h-rows per slice (TH + 2 halo)
#define SLICE   (C_IN * ROWS * 32)   // 960 floats per depth slice
#define DPB     15     // output depths per block (depth-split x2)
#define SPB     17     // input slices this block touches (DPB + 2)
#define OUT_ELEMS (N_BATCH * C_OUT * HW_OUT * HW_OUT)   // 5,529,600

// ---- weights transpose: wt[tap][c], tap=((ci*3+kd)*3+kh)*3+kw; c-pairs -> v2f
__global__ void prep_weights(const float* __restrict__ w, float* __restrict__ wt) {
    int i = blockIdx.x * blockDim.x + threadIdx.x;
    if (i < 81 * C_OUT) {
        int tap = i / C_OUT;
        int c   = i - tap * C_OUT;
        wt[i] = w[c * 81 + tap];
    }
}

// ---- init d_out (used as uint key buffer) to +inf key
__global__ void init_keys(uint4* __restrict__ k, int nq) {
    int i = blockIdx.x * blockDim.x + threadIdx.x;
    if (i < nq) k[i] = make_uint4(~0u, ~0u, ~0u, ~0u);
}

static __device__ __forceinline__ v2f fma2(v2f a, float b, v2f c) {
    v2f bb = {b, b};
    return __builtin_elementwise_fma(a, bb, c);   // -> v_pk_fma_f32
}
static __device__ __forceinline__ v2f min2(v2f a, v2f b) {
    return __builtin_elementwise_min(a, b);
}
// order-preserving float->uint key (monotone): uint atomicMin == float min
static __device__ __forceinline__ unsigned fkey(float f) {
    unsigned u = __float_as_uint(f);
    return (u & 0x80000000u) ? ~u : (u | 0x80000000u);
}

__global__ __launch_bounds__(256) void conv3d_min_part(
    const float* __restrict__ x, const float* __restrict__ wt_,
    unsigned* __restrict__ keys)
{
    __shared__ __align__(16) float lds[4 * SLICE];
    const v2f* __restrict__ wt2 = (const v2f*)wt_;

    const int tid = threadIdx.x;
    const int w   = tid & 31;
    const int ty  = tid >> 5;
    const int bid = blockIdx.x;          // grid 2048 = 256n x 4ht x 2dh
    const int n   = bid >> 3;
    const int ht  = (bid >> 1) & 3;
    const int dh  = bid & 1;
    const int h0  = ht * TH;
    const int h   = h0 + ty;
    const int d0  = dh * DPB;
    const bool active = (w < HW_OUT) && (h < HW_OUT);
    const int vb = ty * 32 + w;

    // staging: 240 threads move one float4 per slice
    const int  sci  = tid / 80;
    const int  srem = tid - sci * 80;
    const int  srow = srem >> 3;
    const int  sc4  = (srem & 7) * 4;
    const bool sth  = (tid < 240) && (h0 + srow < HW_IN);
    const size_t sgbase =
        ((size_t)(n * C_IN + sci) * D_IN + d0) * (HW_IN * HW_IN)
        + (size_t)(h0 + srow) * HW_IN + sc4;
    const int sldst = (sci * ROWS + srow) * 32 + sc4;

    auto load_slice = [&](int s) -> float4 {
        float4 v = make_float4(0.f, 0.f, 0.f, 0.f);
        if (sth && s < SPB)
            v = *reinterpret_cast<const float4*>(&x[sgbase + (size_t)s * (HW_IN * HW_IN)]);
        return v;
    };
    auto write_slice = [&](float* base, float4 v, int s) {
        if (sth && s < SPB)
            *reinterpret_cast<float4*>(&base[sldst]) = v;
    };

    float* q0 = &lds[0 * SLICE];   // slice 2p
    float* q1 = &lds[1 * SLICE];   // slice 2p+1
    float* q2 = &lds[2 * SLICE];   // slice 2p+2
    float* q3 = &lds[3 * SLICE];   // slice 2p+3

    {   // prologue: slices 0..3
        float4 a = load_slice(0), b = load_slice(1), c = load_slice(2), d = load_slice(3);
        write_slice(q0, a, 0); write_slice(q1, b, 1);
        write_slice(q2, c, 2); write_slice(q3, d, 3);
    }

    v2f mn[NPAIR];
#pragma unroll
    for (int j = 0; j < NPAIR; ++j) mn[j] = (v2f){FLT_MAX, FLT_MAX};

    // 7 depth-pairs: depths (2p, 2p+1) from slices 2p..2p+3
    for (int p = 0; p < 7; ++p) {
        float4 nx0 = load_slice(2 * p + 4);       // issue early
        float4 nx1 = load_slice(2 * p + 5);
        __syncthreads();                          // prior ds_writes visible
        if (active) {
            v2f acc0[NPAIR], acc1[NPAIR];
#pragma unroll
            for (int j = 0; j < NPAIR; ++j) { acc0[j] = (v2f){0.f,0.f}; acc1[j] = (v2f){0.f,0.f}; }
#pragma unroll
            for (int ci = 0; ci < C_IN; ++ci) {
#pragma unroll
                for (int kh = 0; kh < 3; ++kh) {
                    const int ro = ci * (ROWS * 32) + kh * 32 + vb;
                    float xs0[3], xs1[3], xs2[3], xs3[3];
#pragma unroll
                    for (int kw = 0; kw < 3; ++kw) {
                        xs0[kw] = q0[ro + kw]; xs1[kw] = q1[ro + kw];
                        xs2[kw] = q2[ro + kw]; xs3[kw] = q3[ro + kw];
                    }
#pragma unroll
                    for (int kw = 0; kw < 3; ++kw) {
#pragma unroll
                        for (int kd = 0; kd < 3; ++kd) {
                            const v2f* wp = wt2 + (((ci * 3 + kd) * 3 + kh) * 3 + kw) * NPAIR;
                            const float xa = (kd == 0) ? xs0[kw] : (kd == 1) ? xs1[kw] : xs2[kw];
                            const float xb = (kd == 0) ? xs1[kw] : (kd == 1) ? xs2[kw] : xs3[kw];
#pragma unroll
                            for (int j = 0; j < NPAIR; ++j) {
                                acc0[j] = fma2(wp[j], xa, acc0[j]);   // weight reused x2
                                acc1[j] = fma2(wp[j], xb, acc1[j]);
                            }
                        }
                    }
                }
            }
#pragma unroll
            for (int j = 0; j < NPAIR; ++j) mn[j] = min2(mn[j], min2(acc0[j], acc1[j]));
        }
        __syncthreads();                          // all reads of retiring slots done
        write_slice(q0, nx0, 2 * p + 4);          // overwrite retired slices 2p, 2p+1
        write_slice(q1, nx1, 2 * p + 5);
        float* t0 = q0; float* t1 = q1;
        q0 = q2; q1 = q3; q2 = t0; q3 = t1;       // invariant: q0 holds slice 2(p+1)
    }

    // leftover depth 14: slices 14,15,16 in q0,q1,q2
    __syncthreads();
    if (active) {
        v2f acc0[NPAIR];
#pragma unroll
        for (int j = 0; j < NPAIR; ++j) acc0[j] = (v2f){0.f, 0.f};
#pragma unroll
        for (int ci = 0; ci < C_IN; ++ci) {
#pragma unroll
            for (int kh = 0; kh < 3; ++kh) {
                const int ro = ci * (ROWS * 32) + kh * 32 + vb;
                float xs0[3], xs1[3], xs2[3];
#pragma unroll
                for (int kw = 0; kw < 3; ++kw) {
                    xs0[kw] = q0[ro + kw]; xs1[kw] = q1[ro + kw]; xs2[kw] = q2[ro + kw];
                }
#pragma unroll
                for (int kw = 0; kw < 3; ++kw) {
#pragma unroll
                    for (int kd = 0; kd < 3; ++kd) {
                        const v2f* wp = wt2 + (((ci * 3 + kd) * 3 + kh) * 3 + kw) * NPAIR;
                        const float xa = (kd == 0) ? xs0[kw] : (kd == 1) ? xs1[kw] : xs2[kw];
#pragma unroll
                        for (int j = 0; j < NPAIR; ++j) acc0[j] = fma2(wp[j], xa, acc0[j]);
                    }
                }
            }
        }
#pragma unroll
        for (int j = 0; j < NPAIR; ++j) mn[j] = min2(mn[j], acc0[j]);

        // publish partial mins: bitwise-exact float min via uint atomicMin
        const size_t obase = ((size_t)n * C_OUT) * (HW_OUT * HW_OUT) + h * HW_OUT + w;
#pragma unroll
        for (int j = 0; j < NPAIR; ++j) {
            atomicMin(&keys[obase + (size_t)(2 * j)     * (HW_OUT * HW_OUT)], fkey(mn[j].x));
            atomicMin(&keys[obase + (size_t)(2 * j + 1) * (HW_OUT * HW_OUT)], fkey(mn[j].y));
        }
    }
}

// ---- un-key + bias + softmax, in place over d_out
__global__ __launch_bounds__(256) void min_softmax_finish(
    unsigned* buf, const float* __restrict__ bias)
{
    const int i = blockIdx.x * blockDim.x + threadIdx.x;   // over N*30*30 columns
    if (i >= N_BATCH * HW_OUT * HW_OUT) return;
    const int n   = i / (HW_OUT * HW_OUT);
    const int rem = i - n * (HW_OUT * HW_OUT);
    const size_t base = (size_t)n * (C_OUT * HW_OUT * HW_OUT) + rem;

    float v[C_OUT];
#pragma unroll
    for (int c = 0; c < C_OUT; ++c) {
        const unsigned k = buf[base + (size_t)c * (HW_OUT * HW_OUT)];
        const unsigned u = (k & 0x80000000u) ? (k ^ 0x80000000u) : ~k;
        v[c] = __uint_as_float(u) + bias[c];     // bias commutes with min over depth
    }
    float m = v[0];
#pragma unroll
    for (int c = 1; c < C_OUT; ++c) m = fmaxf(m, v[c]);
    float s = 0.f;
#pragma unroll
    for (int c = 0; c < C_OUT; ++c) { v[c] = expf(v[c] - m); s += v[c]; }
    const float inv = 1.0f / s;
#pragma unroll
    for (int c = 0; c < C_OUT; ++c)
        reinterpret_cast<float*>(buf)[base + (size_t)c * (HW_OUT * HW_OUT)] = v[c] * inv;
}

extern "C" void kernel_launch(void* const* d_in, const int* in_sizes, int n_in,
                              void* d_out, int out_size, void* d_ws, size_t ws_size,
                              hipStream_t stream) {
    const float* x    = (const float*)d_in[0];
    const float* wgt  = (const float*)d_in[1];
    const float* bias = (const float*)d_in[2];
    float* wt = (float*)d_ws;                      // 7776 B scratch

    prep_weights<<<dim3((81 * C_OUT + 255) / 256), 256, 0, stream>>>(wgt, wt);
    init_keys<<<dim3((OUT_ELEMS / 4 + 255) / 256), 256, 0, stream>>>((uint4*)d_out, OUT_ELEMS / 4);
    conv3d_min_part<<<dim3(N_BATCH * 4 * 2), 256, 0, stream>>>(x, wt, (unsigned*)d_out);
    min_softmax_finish<<<dim3((N_BATCH * HW_OUT * HW_OUT + 255) / 256), 256, 0, stream>>>(
        (unsigned*)d_out, bias);
}

// Round 5
// 287.288 us; speedup vs baseline: 1.9062x; 1.0824x over previous
//
#include <hip/hip_runtime.h>
#include <math.h>
#include <float.h>

typedef float v2f __attribute__((ext_vector_type(2)));

#define N_BATCH 256
#define C_IN    3
#define D_IN    32
#define HW_IN   32
#define C_OUT   24
#define NPAIR   12
#define D_OUTS  30
#define HW_OUT  30
#define TH      8
#define ROWS    10
#define SLICE   (C_IN * ROWS * 32)   // 960 floats per depth slice
#define NSLOT   6                    // 23040 B LDS ring
#define DPB     15
#define SPB     17
#define OUT_ELEMS (N_BATCH * C_OUT * HW_OUT * HW_OUT)

// weights -> wt[(((ci*3+kh)*3+kd)*3+kw)*24 + c] : linear +108 v2f per (ci,kh) step
__global__ void prep_weights(const float* __restrict__ w, float* __restrict__ wt) {
    int i = blockIdx.x * blockDim.x + threadIdx.x;
    if (i < 81 * C_OUT) {
        int tap = i / C_OUT;
        int c   = i - tap * C_OUT;
        int kw = tap % 3, t1 = tap / 3;
        int kd = t1 % 3,  t2 = t1 / 3;
        int kh = t2 % 3,  ci = t2 / 3;
        wt[i] = w[(((c * 3 + ci) * 3 + kd) * 3 + kh) * 3 + kw];
    }
}

__global__ void init_keys(uint4* __restrict__ k, int nq) {
    int i = blockIdx.x * blockDim.x + threadIdx.x;
    if (i < nq) k[i] = make_uint4(~0u, ~0u, ~0u, ~0u);
}

static __device__ __forceinline__ v2f fma2(v2f a, float b, v2f c) {
    v2f bb = {b, b};
    return __builtin_elementwise_fma(a, bb, c);   // v_pk_fma_f32
}
static __device__ __forceinline__ v2f min2(v2f a, v2f b) {
    return __builtin_elementwise_min(a, b);
}
static __device__ __forceinline__ unsigned fkey(float f) {
    unsigned u = __float_as_uint(f);
    return (u & 0x80000000u) ? ~u : (u | 0x80000000u);
}

static __device__ __forceinline__ void gload16(const float* g, float* l) {
#if __has_builtin(__builtin_amdgcn_global_load_lds)
    __builtin_amdgcn_global_load_lds(
        (const __attribute__((address_space(1))) unsigned int*)g,
        (__attribute__((address_space(3))) unsigned int*)l, 16, 0, 0);
#else
    *reinterpret_cast<float4*>(l) = *reinterpret_cast<const float4*>(g);
#endif
}

// 4-slice compute: depths (acc0: A,B,C) and (acc1: B,C,D). Runtime slot bases.
static __device__ __forceinline__ void comp4(
    const float* __restrict__ lds, const v2f* __restrict__ wt2,
    int bA, int bB, int bC, int bD, v2f mn[NPAIR], bool active)
{
    if (!active) return;
    v2f a0[NPAIR], a1[NPAIR];
#pragma unroll
    for (int j = 0; j < NPAIR; ++j) { a0[j] = (v2f){0.f, 0.f}; a1[j] = (v2f){0.f, 0.f}; }
    int wb = 0;
#pragma clang loop unroll(disable)
    for (int ci = 0; ci < C_IN; ++ci) {
#pragma clang loop unroll(disable)
        for (int kh = 0; kh < 3; ++kh) {
            float xA[3], xB[3], xC[3], xD[3];
#pragma unroll
            for (int kw = 0; kw < 3; ++kw) {
                xA[kw] = lds[bA + kw]; xB[kw] = lds[bB + kw];
                xC[kw] = lds[bC + kw]; xD[kw] = lds[bD + kw];
            }
#pragma unroll
            for (int kd = 0; kd < 3; ++kd) {
#pragma unroll
                for (int kw = 0; kw < 3; ++kw) {
                    const v2f* wp = &wt2[wb + (kd * 3 + kw) * NPAIR];
                    const float xa = (kd == 0) ? xA[kw] : (kd == 1) ? xB[kw] : xC[kw];
                    const float xb = (kd == 0) ? xB[kw] : (kd == 1) ? xC[kw] : xD[kw];
#pragma unroll
                    for (int j = 0; j < NPAIR; ++j) {
                        a0[j] = fma2(wp[j], xa, a0[j]);
                        a1[j] = fma2(wp[j], xb, a1[j]);
                    }
                }
            }
            bA += 32; bB += 32; bC += 32; bD += 32; wb += 108;
        }
        bA += 224; bB += 224; bC += 224; bD += 224;
    }
#pragma unroll
    for (int j = 0; j < NPAIR; ++j) mn[j] = min2(mn[j], min2(a0[j], a1[j]));
}

// 3-slice tail (single depth: A,B,C)
static __device__ __forceinline__ void comp3(
    const float* __restrict__ lds, const v2f* __restrict__ wt2,
    int bA, int bB, int bC, v2f mn[NPAIR], bool active)
{
    if (!active) return;
    v2f a0[NPAIR];
#pragma unroll
    for (int j = 0; j < NPAIR; ++j) a0[j] = (v2f){0.f, 0.f};
    int wb = 0;
#pragma clang loop unroll(disable)
    for (int ci = 0; ci < C_IN; ++ci) {
#pragma clang loop unroll(disable)
        for (int kh = 0; kh < 3; ++kh) {
            float xA[3], xB[3], xC[3];
#pragma unroll
            for (int kw = 0; kw < 3; ++kw) {
                xA[kw] = lds[bA + kw]; xB[kw] = lds[bB + kw]; xC[kw] = lds[bC + kw];
            }
#pragma unroll
            for (int kd = 0; kd < 3; ++kd) {
#pragma unroll
                for (int kw = 0; kw < 3; ++kw) {
                    const v2f* wp = &wt2[wb + (kd * 3 + kw) * NPAIR];
                    const float xa = (kd == 0) ? xA[kw] : (kd == 1) ? xB[kw] : xC[kw];
#pragma unroll
                    for (int j = 0; j < NPAIR; ++j) a0[j] = fma2(wp[j], xa, a0[j]);
                }
            }
            bA += 32; bB += 32; bC += 32; wb += 108;
        }
        bA += 224; bB += 224; bC += 224;
    }
#pragma unroll
    for (int j = 0; j < NPAIR; ++j) mn[j] = min2(mn[j], a0[j]);
}

__global__ __launch_bounds__(256) void conv3d_min_part(
    const float* __restrict__ x, const float* __restrict__ wt_,
    unsigned* __restrict__ keys)
{
    __shared__ __align__(16) float lds[NSLOT * SLICE];
    const v2f* __restrict__ wt2 = (const v2f*)wt_;

    const int tid = threadIdx.x;
    const int w   = tid & 31;
    const int ty  = tid >> 5;
    const int bid = blockIdx.x;              // 2048 = 256n x 4ht x 2dh
    const int n   = bid >> 3;
    const int ht  = (bid >> 1) & 3;
    const int dh  = bid & 1;
    const int h0  = ht * TH;
    const int h   = h0 + ty;
    const int d0  = dh * DPB;
    const bool active = (w < HW_OUT) && (h < HW_OUT);
    const int vb = ty * 32 + w;

    // staging: 240 threads, lds byte offset = tid*16 (= wave_base + lane*16)
    const int  sci  = tid / 80;
    const int  srem = tid - sci * 80;
    const int  srow = srem >> 3;
    const bool sth  = (tid < 240) && (h0 + srow < HW_IN);
    const size_t sgelem =
        ((size_t)(n * C_IN + sci) * D_IN + d0) * 1024
        + (size_t)(h0 + srow) * 32 + (srem & 7) * 4;
    float* const lwave = &lds[(tid >> 6) * 256];   // wave-uniform base within a slot

    auto stage = [&](int slotOff, int s) {         // slotOff in floats, s = slice idx
        if (s < SPB) {
            if (sth) gload16(&x[sgelem + (size_t)s * 1024], lwave + slotOff);
        }
    };

    // prologue: slices 0..3 -> slots 0..3
    stage(0 * SLICE, 0); stage(1 * SLICE, 1); stage(2 * SLICE, 2); stage(3 * SLICE, 3);

    v2f mn[NPAIR];
#pragma unroll
    for (int j = 0; j < NPAIR; ++j) mn[j] = (v2f){FLT_MAX, FLT_MAX};

    int sA = 0, sB = 1, sC = 2, sD = 3, sE = 4, sF = 5;
#pragma clang loop unroll(disable)
    for (int p = 0; p < 7; ++p) {
        __syncthreads();                           // drains prior gloads (covered by compute)
        stage(sE * SLICE, 2 * p + 4);              // async into free slots
        stage(sF * SLICE, 2 * p + 5);
        comp4(lds, wt2, sA * SLICE + vb, sB * SLICE + vb,
                       sC * SLICE + vb, sD * SLICE + vb, mn, active);
        int nA = sC, nB = sD, nC = sE, nD = sF, nE = sA, nF = sB;
        sA = nA; sB = nB; sC = nC; sD = nD; sE = nE; sF = nF;
    }
    __syncthreads();                               // drains p=6's gload (slice 16)
    comp3(lds, wt2, sA * SLICE + vb, sB * SLICE + vb, sC * SLICE + vb, mn, active);

    if (active) {
        const size_t obase = ((size_t)n * C_OUT) * (HW_OUT * HW_OUT) + h * HW_OUT + w;
#pragma unroll
        for (int j = 0; j < NPAIR; ++j) {
            atomicMin(&keys[obase + (size_t)(2 * j)     * (HW_OUT * HW_OUT)], fkey(mn[j].x));
            atomicMin(&keys[obase + (size_t)(2 * j + 1) * (HW_OUT * HW_OUT)], fkey(mn[j].y));
        }
    }
}

__global__ __launch_bounds__(256) void min_softmax_finish(
    unsigned* buf, const float* __restrict__ bias)
{
    const int i = blockIdx.x * blockDim.x + threadIdx.x;
    if (i >= N_BATCH * HW_OUT * HW_OUT) return;
    const int n   = i / (HW_OUT * HW_OUT);
    const int rem = i - n * (HW_OUT * HW_OUT);
    const size_t base = (size_t)n * (C_OUT * HW_OUT * HW_OUT) + rem;

    float v[C_OUT];
#pragma unroll
    for (int c = 0; c < C_OUT; ++c) {
        const unsigned k = buf[base + (size_t)c * (HW_OUT * HW_OUT)];
        const unsigned u = (k & 0x80000000u) ? (k ^ 0x80000000u) : ~k;
        v[c] = __uint_as_float(u) + bias[c];
    }
    float m = v[0];
#pragma unroll
    for (int c = 1; c < C_OUT; ++c) m = fmaxf(m, v[c]);
    float s = 0.f;
#pragma unroll
    for (int c = 0; c < C_OUT; ++c) { v[c] = expf(v[c] - m); s += v[c]; }
    const float inv = 1.0f / s;
#pragma unroll
    for (int c = 0; c < C_OUT; ++c)
        reinterpret_cast<float*>(buf)[base + (size_t)c * (HW_OUT * HW_OUT)] = v[c] * inv;
}

extern "C" void kernel_launch(void* const* d_in, const int* in_sizes, int n_in,
                              void* d_out, int out_size, void* d_ws, size_t ws_size,
                              hipStream_t stream) {
    const float* x    = (const float*)d_in[0];
    const float* wgt  = (const float*)d_in[1];
    const float* bias = (const float*)d_in[2];
    float* wt = (float*)d_ws;

    prep_weights<<<dim3((81 * C_OUT + 255) / 256), 256, 0, stream>>>(wgt, wt);
    init_keys<<<dim3((OUT_ELEMS / 4 + 255) / 256), 256, 0, stream>>>((uint4*)d_out, OUT_ELEMS / 4);
    conv3d_min_part<<<dim3(N_BATCH * 4 * 2), 256, 0, stream>>>(x, wt, (unsigned*)d_out);
    min_softmax_finish<<<dim3((N_BATCH * HW_OUT * HW_OUT + 255) / 256), 256, 0, stream>>>(
        (unsigned*)d_out, bias);
}

// Round 6
// 242.874 us; speedup vs baseline: 2.2548x; 1.1829x over previous
//
#include <hip/hip_runtime.h>
#include <math.h>
#include <float.h>
#include <type_traits>

typedef short s16x8 __attribute__((ext_vector_type(8)));
typedef float f32x4 __attribute__((ext_vector_type(4)));

#define N_BATCH 256

// round-to-nearest-even float -> bf16 bits
static __device__ __host__ __forceinline__ unsigned short bf16r(float f) {
    unsigned u = __float_as_uint(f);
    unsigned r = (u + 0x7fffu + ((u >> 16) & 1u)) >> 16;
    return (unsigned short)r;
}
static __device__ __forceinline__ float bf16f(unsigned short s) {
    return __uint_as_float((unsigned)s << 16);
}
static __device__ __forceinline__ f32x4 MM(s16x8 a, s16x8 b, f32x4 c) {
    return __builtin_amdgcn_mfma_f32_16x16x32_bf16(a, b, c, 0, 0, 0);
}

// Build split-weight A-fragments in d_ws.
// Layout: fragset f = (kd*2+cht)*2+hs (hs: 0=hi,1=lo); dword i = f*256 + lane*4 + r.
// Lane l holds A[ch = cht*16 + (l&15)][k = 8*(l>>4) + 2r + half]; k = ci*9+kh*3+kw.
__global__ void prep_weights(const float* __restrict__ w, unsigned* __restrict__ ws) {
    int i = blockIdx.x * 256 + threadIdx.x;          // 3072 dwords total
    if (i >= 3072) return;
    int f = i >> 8, rem = i & 255;
    int lane = rem >> 2, r = rem & 3;
    int kd = f >> 2, cht = (f >> 1) & 1, hs = f & 1;
    int g = lane >> 4, chl = lane & 15;
    int ch = cht * 16 + chl;
    unsigned out = 0;
    for (int half = 0; half < 2; ++half) {
        int k = 8 * g + 2 * r + half;
        unsigned short bits = 0;                     // exact zero pad (kills garbage B cols)
        if (ch < 24 && k < 27) {
            int ci = k / 9, kh = (k % 9) / 3, kw = k % 3;
            float wv = w[(((ch * 3 + ci) * 3 + kd) * 3 + kh) * 3 + kw];
            unsigned short hi = bf16r(wv);
            bits = (hs == 0) ? hi : bf16r(wv - bf16f(hi));
        }
        out |= (unsigned)bits << (16 * half);
    }
    ws[i] = out;
}

__global__ __launch_bounds__(256) void conv_mfma(
    const float* __restrict__ x, const char* __restrict__ wsp,
    const float* __restrict__ bias, float* __restrict__ out)
{
    // xs: double-buffered split slice rows [slot][hs][ci*192 + r6*32 + w]
    __shared__ unsigned short xsbuf[2][2][576];
    // P panels: [wave][wtile][hs][m*32 + k] (pos-major, 64B rows)
    __shared__ __align__(16) unsigned short pbuf[4][2][2][512];

    const int tid  = threadIdx.x;
    const int lane = tid & 63;
    const int wid  = tid >> 6;
    const int g    = lane >> 4;
    const int m    = lane & 15;
    const int n    = blockIdx.x >> 3;
    const int h0   = (blockIdx.x & 7) * 4;
    const int h    = h0 + wid;
    const bool hOK = (h < 30);

    // zero LDS (pad-column reads must be finite: 0 * Inf = NaN hazard)
    for (int i = tid; i < 1152 / 2; i += 256) ((unsigned*)&xsbuf[0][0][0])[i] = 0u;
    for (int i = tid; i < 8192 / 2; i += 256) ((unsigned*)&pbuf[0][0][0][0])[i] = 0u;

    // ---- staging addresses: thread covers elems e1=2*tid,2*tid+1 and (wave0) 512+tid
    auto eaddr = [&](int e) -> const char* {
        int ci = e / 192, loc = e - ci * 192;
        int r = loc >> 5, ww = loc & 31;
        int row = h0 + r; if (row > 31) row = 31;
        size_t elem = ((size_t)(n * 3 + ci) * 32) * 1024 + (size_t)row * 32 + ww;
        return (const char*)(x + elem);
    };
    const char* xb1 = eaddr(2 * tid);
    const char* xb2 = eaddr(512 + (tid & 63));       // used by wave 0 only

    // ---- build tables: per s4-step, source elem offsets for the k-pair (w0 added at use)
    int eo0[4], eo1[4];
#pragma unroll
    for (int s4 = 0; s4 < 4; ++s4) {
        int kp = g + 4 * s4;
        int k0 = 2 * kp, k1 = 2 * kp + 1;
        int ci0 = k0 / 9, kh0 = (k0 % 9) / 3, kw0 = k0 % 3;
        int ci1 = k1 / 9, kh1 = (k1 % 9) / 3, kw1 = k1 % 3;
        eo0[s4] = ci0 * 192 + (wid + kh0) * 32 + m + kw0;
        eo1[s4] = ci1 * 192 + (wid + kh1) * 32 + m + kw1;
    }
    const int pdst = m * 64 + g * 4;                 // P write byte offset (+16 per s4)
    const int boff = m * 64 + g * 16;                // B-frag read byte offset

    f32x4 acc[3][2][2];                              // [depth%3][cht][wt] — static idx only
    f32x4 mn[2][2];
#pragma unroll
    for (int a = 0; a < 3; ++a)
#pragma unroll
        for (int b = 0; b < 2; ++b)
#pragma unroll
            for (int c = 0; c < 2; ++c) acc[a][b][c] = (f32x4){0.f, 0.f, 0.f, 0.f};
#pragma unroll
    for (int b = 0; b < 2; ++b)
#pragma unroll
        for (int c = 0; c < 2; ++c) mn[b][c] = (f32x4){FLT_MAX, FLT_MAX, FLT_MAX, FLT_MAX};

    float2 sv1 = *(const float2*)xb1;                // prologue: slice 0 in flight
    float  sv2 = (wid == 0) ? *(const float*)xb2 : 0.f;

    const char* wl = wsp + (size_t)lane * 16;

    auto step = [&](int s, auto smc) {
        constexpr int SM = decltype(smc)::value;     // == s % 3
        constexpr int S0 = SM;                       // kd=0 -> depth s
        constexpr int S1 = (SM + 2) % 3;             // kd=1 -> depth s-1
        constexpr int S2 = (SM + 1) % 3;             // kd=2 -> depth s-2 (retires)
        const int slot = s & 1;

        {   // write split slice into xs ring
            unsigned short hA = bf16r(sv1.x), hB = bf16r(sv1.y);
            unsigned short lA = bf16r(sv1.x - bf16f(hA)), lB = bf16r(sv1.y - bf16f(hB));
            *(unsigned*)&xsbuf[slot][0][2 * tid] = (unsigned)hA | ((unsigned)hB << 16);
            *(unsigned*)&xsbuf[slot][1][2 * tid] = (unsigned)lA | ((unsigned)lB << 16);
            if (wid == 0) {
                unsigned short hC = bf16r(sv2);
                xsbuf[slot][0][512 + tid] = hC;
                xsbuf[slot][1][512 + tid] = bf16r(sv2 - bf16f(hC));
            }
        }
        __syncthreads();
        if (s + 1 < 32) {                            // prefetch next slice under compute
            sv1 = *(const float2*)(xb1 + (size_t)(s + 1) * 4096);
            if (wid == 0) sv2 = *(const float*)(xb2 + (size_t)(s + 1) * 4096);
        }
        if (hOK) {
            // ---- build P panels (im2col transpose, wave-private)
#pragma unroll
            for (int s4 = 0; s4 < 4; ++s4) {
#pragma unroll
                for (int wt = 0; wt < 2; ++wt) {
                    const int ea = eo0[s4] + wt * 14;
                    const int eb = eo1[s4] + wt * 14;
#pragma unroll
                    for (int hs = 0; hs < 2; ++hs) {
                        unsigned lo = xsbuf[slot][hs][ea];
                        unsigned hi = xsbuf[slot][hs][eb];
                        *(unsigned*)((char*)&pbuf[wid][wt][hs][0] + pdst + s4 * 16)
                            = lo | (hi << 16);
                    }
                }
            }
            // ---- MFMA: one K=32 mfma covers all 27 taps of this slice
            auto mmkd = [&](int kd, f32x4 (&as)[2][2]) {
                const char* wb = wl + (size_t)kd * 4096;
                s16x8 ah0 = *(const s16x8*)(wb);
                s16x8 al0 = *(const s16x8*)(wb + 1024);
                s16x8 ah1 = *(const s16x8*)(wb + 2048);
                s16x8 al1 = *(const s16x8*)(wb + 3072);
#pragma unroll
                for (int wt = 0; wt < 2; ++wt) {
                    s16x8 bh = *(const s16x8*)((const char*)&pbuf[wid][wt][0][0] + boff);
                    s16x8 bl = *(const s16x8*)((const char*)&pbuf[wid][wt][1][0] + boff);
                    as[0][wt] = MM(ah0, bh, as[0][wt]);
                    as[0][wt] = MM(al0, bh, as[0][wt]);
                    as[0][wt] = MM(ah0, bl, as[0][wt]);
                    as[1][wt] = MM(ah1, bh, as[1][wt]);
                    as[1][wt] = MM(al1, bh, as[1][wt]);
                    as[1][wt] = MM(ah1, bl, as[1][wt]);
                }
            };
            if (s <= 29)           mmkd(0, acc[S0]);
            if (s >= 1 && s <= 30) mmkd(1, acc[S1]);
            if (s >= 2)            mmkd(2, acc[S2]);
            if (s >= 2) {                            // retire depth s-2 into running min
#pragma unroll
                for (int cht = 0; cht < 2; ++cht)
#pragma unroll
                    for (int wt = 0; wt < 2; ++wt) {
#pragma unroll
                        for (int r = 0; r < 4; ++r)
                            mn[cht][wt][r] = fminf(mn[cht][wt][r], acc[S2][cht][wt][r]);
                        acc[S2][cht][wt] = (f32x4){0.f, 0.f, 0.f, 0.f};
                    }
            }
        }
    };

    for (int sb = 0; sb < 32; sb += 3) {
        step(sb, std::integral_constant<int, 0>{});
        if (sb + 1 < 32) step(sb + 1, std::integral_constant<int, 1>{});
        if (sb + 2 < 32) step(sb + 2, std::integral_constant<int, 2>{});
    }

    // ---- bias + softmax over channels (4-lane group: lanes m, m+16, m+32, m+48)
    if (hOK) {
#pragma unroll
        for (int wt = 0; wt < 2; ++wt) {
            float vals[8];
            bool  vld[8];
            float mx = -FLT_MAX;
#pragma unroll
            for (int cht = 0; cht < 2; ++cht)
#pragma unroll
                for (int r = 0; r < 4; ++r) {
                    int c = cht * 16 + 4 * g + r;
                    bool v = (c < 24);
                    float val = -FLT_MAX;
                    if (v) val = mn[cht][wt][r] + bias[c];
                    vals[cht * 4 + r] = val;
                    vld[cht * 4 + r] = v;
                    mx = fmaxf(mx, val);
                }
            mx = fmaxf(mx, __shfl_xor(mx, 16));
            mx = fmaxf(mx, __shfl_xor(mx, 32));
            float sum = 0.f;
#pragma unroll
            for (int j = 0; j < 8; ++j) {
                vals[j] = vld[j] ? expf(vals[j] - mx) : 0.f;
                sum += vals[j];
            }
            sum += __shfl_xor(sum, 16);
            sum += __shfl_xor(sum, 32);
            const float inv = 1.0f / sum;
            const int w = wt * 14 + m;               // wt0: w=0..15; wt1: w=16..29 (m>=2)
            if (wt == 0 || m >= 2) {
#pragma unroll
                for (int cht = 0; cht < 2; ++cht)
#pragma unroll
                    for (int r = 0; r < 4; ++r) {
                        int c = cht * 16 + 4 * g + r;
                        if (c < 24)
                            out[((size_t)(n * 24 + c) * 30 + h) * 30 + w]
                                = vals[cht * 4 + r] * inv;
                    }
            }
        }
    }
}

extern "C" void kernel_launch(void* const* d_in, const int* in_sizes, int n_in,
                              void* d_out, int out_size, void* d_ws, size_t ws_size,
                              hipStream_t stream) {
    const float* x    = (const float*)d_in[0];
    const float* wgt  = (const float*)d_in[1];
    const float* bias = (const float*)d_in[2];
    prep_weights<<<12, 256, 0, stream>>>(wgt, (unsigned*)d_ws);     // 12288 B of d_ws
    conv_mfma<<<N_BATCH * 8, 256, 0, stream>>>(x, (const char*)d_ws, bias, (float*)d_out);
}

// Round 7
// 127.160 us; speedup vs baseline: 4.3067x; 1.9100x over previous
//
#include <hip/hip_runtime.h>
#include <math.h>
#include <float.h>
#include <type_traits>

typedef short s16x8 __attribute__((ext_vector_type(8)));
typedef float f32x4 __attribute__((ext_vector_type(4)));

#define N_BATCH 256

// round-to-nearest-even float -> bf16 bits
static __device__ __host__ __forceinline__ unsigned short bf16r(float f) {
    unsigned u = __float_as_uint(f);
    unsigned r = (u + 0x7fffu + ((u >> 16) & 1u)) >> 16;
    return (unsigned short)r;
}
static __device__ __forceinline__ float bf16f(unsigned short s) {
    return __uint_as_float((unsigned)s << 16);
}
static __device__ __forceinline__ f32x4 MM(s16x8 a, s16x8 b, f32x4 c) {
    return __builtin_amdgcn_mfma_f32_16x16x32_bf16(a, b, c, 0, 0, 0);
}

// Split-weight A-fragments in d_ws (verified layout, round 6).
// fragset f = (kd*2+cht)*2+hs ; dword i = f*256 + lane*4 + r.
// Lane l holds A[ch = cht*16 + (l&15)][k = 8*(l>>4) + 2r + half]; k = ci*9+kh*3+kw.
__global__ void prep_weights(const float* __restrict__ w, unsigned* __restrict__ ws) {
    int i = blockIdx.x * 256 + threadIdx.x;          // 3072 dwords total
    if (i >= 3072) return;
    int f = i >> 8, rem = i & 255;
    int lane = rem >> 2, r = rem & 3;
    int kd = f >> 2, cht = (f >> 1) & 1, hs = f & 1;
    int g = lane >> 4, chl = lane & 15;
    int ch = cht * 16 + chl;
    unsigned out = 0;
    for (int half = 0; half < 2; ++half) {
        int k = 8 * g + 2 * r + half;
        unsigned short bits = 0;                     // exact zero pad
        if (ch < 24 && k < 27) {
            int ci = k / 9, kh = (k % 9) / 3, kw = k % 3;
            float wv = w[(((ch * 3 + ci) * 3 + kd) * 3 + kh) * 3 + kw];
            unsigned short hi = bf16r(wv);
            bits = (hs == 0) ? hi : bf16r(wv - bf16f(hi));
        }
        out |= (unsigned)bits << (16 * half);
    }
    ws[i] = out;
}

__global__ __launch_bounds__(256) void conv_mfma(
    const float* __restrict__ x, const char* __restrict__ wsp,
    const float* __restrict__ bias, float* __restrict__ out)
{
    // split slice ring: [slot][hs][ci*192 + r6*32 + w] shorts — 4608 B total
    __shared__ unsigned short xsbuf[2][2][576];

    const int tid  = threadIdx.x;
    const int lane = tid & 63;
    const int wid  = tid >> 6;
    const int g    = lane >> 4;
    const int m    = lane & 15;
    const int n    = blockIdx.x >> 3;
    const int h0   = (blockIdx.x & 7) * 4;
    const int h    = h0 + wid;
    const bool hOK = (h < 30);

    // per-lane gather byte-offsets: frag short j <- tap k=8g+j at col m
    int eo[8];
#pragma unroll
    for (int j = 0; j < 8; ++j) {
        int k = 8 * g + j;
        if (k < 27) {
            int ci = k / 9, r = k - ci * 9;
            int kh = r / 3, kw = r - kh * 3;
            eo[j] = (ci * 192 + (wid + kh) * 32 + m + kw) * 2;
        } else eo[j] = 0;                            // finite garbage * A=0 = 0
    }

    // staging addresses: thread covers elems 2*tid, 2*tid+1 and (wave0) 512+tid
    auto eaddr = [&](int e) -> const char* {
        int ci = e / 192, loc = e - ci * 192;
        int r = loc >> 5, ww = loc & 31;
        int row = h0 + r; if (row > 31) row = 31;
        size_t elem = ((size_t)(n * 3 + ci) * 32) * 1024 + (size_t)row * 32 + ww;
        return (const char*)(x + elem);
    };
    const char* xb1 = eaddr(2 * tid);
    const char* xb2 = eaddr(512 + (tid & 63));       // wave 0 only

    // preload all 12 A-fragments (loop-invariant): 48 VGPRs
    const char* wl = wsp + (size_t)lane * 16;
    s16x8 aH[3][2], aL[3][2];
#pragma unroll
    for (int kd = 0; kd < 3; ++kd) {
        aH[kd][0] = *(const s16x8*)(wl + kd * 4096);
        aL[kd][0] = *(const s16x8*)(wl + kd * 4096 + 1024);
        aH[kd][1] = *(const s16x8*)(wl + kd * 4096 + 2048);
        aL[kd][1] = *(const s16x8*)(wl + kd * 4096 + 3072);
    }

    f32x4 acc[3][2][2];                              // [depth%3][cht][wt]
    f32x4 mn[2][2];
#pragma unroll
    for (int a = 0; a < 3; ++a)
#pragma unroll
        for (int b = 0; b < 2; ++b)
#pragma unroll
            for (int c = 0; c < 2; ++c) acc[a][b][c] = (f32x4){0.f, 0.f, 0.f, 0.f};
#pragma unroll
    for (int b = 0; b < 2; ++b)
#pragma unroll
        for (int c = 0; c < 2; ++c) mn[b][c] = (f32x4){FLT_MAX, FLT_MAX, FLT_MAX, FLT_MAX};

    float2 sv1 = *(const float2*)xb1;                // slice 0 in flight
    float  sv2 = (wid == 0) ? *(const float*)xb2 : 0.f;

    char* const xsb = (char*)&xsbuf[0][0][0];

    auto step = [&](int s, auto smc, auto slc) {
        constexpr int SM = decltype(smc)::value;     // s % 3
        constexpr int SL = decltype(slc)::value;     // s & 1
        constexpr int S0 = SM;                       // kd=0 -> depth s
        constexpr int S1 = (SM + 2) % 3;             // kd=1 -> depth s-1
        constexpr int S2 = (SM + 1) % 3;             // kd=2 -> depth s-2 (retires)

        {   // write split slice into slot SL (stride-1 dwords: conflict-free)
            unsigned short hA = bf16r(sv1.x), hB = bf16r(sv1.y);
            unsigned short lA = bf16r(sv1.x - bf16f(hA)), lB = bf16r(sv1.y - bf16f(hB));
            *(unsigned*)(xsb + SL * 2304 + 0 * 1152 + 4 * tid) = (unsigned)hA | ((unsigned)hB << 16);
            *(unsigned*)(xsb + SL * 2304 + 1 * 1152 + 4 * tid) = (unsigned)lA | ((unsigned)lB << 16);
            if (wid == 0) {
                unsigned short hC = bf16r(sv2);
                *(unsigned short*)(xsb + SL * 2304 + 0 * 1152 + 1024 + 2 * tid) = hC;
                *(unsigned short*)(xsb + SL * 2304 + 1 * 1152 + 1024 + 2 * tid)
                    = bf16r(sv2 - bf16f(hC));
            }
        }
        __syncthreads();
        if (s + 1 < 32) {                            // prefetch next slice under compute
            sv1 = *(const float2*)(xb1 + (size_t)(s + 1) * 4096);
            if (wid == 0) sv2 = *(const float*)(xb2 + (size_t)(s + 1) * 4096);
        }
        if (hOK) {
            // gather B-fragments straight into registers (ds_read_u16, imm offsets)
            s16x8 bf[2][2];                          // [wt][hs]
#pragma unroll
            for (int wt = 0; wt < 2; ++wt)
#pragma unroll
                for (int hs = 0; hs < 2; ++hs)
#pragma unroll
                    for (int j = 0; j < 8; ++j)
                        bf[wt][hs][j] = (short)*(const unsigned short*)
                            (xsb + SL * 2304 + hs * 1152 + wt * 28 + eo[j]);

            auto mmkd = [&](int kd, f32x4 (&as)[2][2]) {
#pragma unroll
                for (int wt = 0; wt < 2; ++wt) {
                    as[0][wt] = MM(aH[kd][0], bf[wt][0], as[0][wt]);
                    as[0][wt] = MM(aL[kd][0], bf[wt][0], as[0][wt]);
                    as[0][wt] = MM(aH[kd][0], bf[wt][1], as[0][wt]);
                    as[1][wt] = MM(aH[kd][1], bf[wt][0], as[1][wt]);
                    as[1][wt] = MM(aL[kd][1], bf[wt][0], as[1][wt]);
                    as[1][wt] = MM(aH[kd][1], bf[wt][1], as[1][wt]);
                }
            };
            if (s <= 29)           mmkd(0, acc[S0]);
            if (s >= 1 && s <= 30) mmkd(1, acc[S1]);
            if (s >= 2)            mmkd(2, acc[S2]);
            if (s >= 2) {                            // retire depth s-2
#pragma unroll
                for (int cht = 0; cht < 2; ++cht)
#pragma unroll
                    for (int wt = 0; wt < 2; ++wt) {
#pragma unroll
                        for (int r = 0; r < 4; ++r)
                            mn[cht][wt][r] = fminf(mn[cht][wt][r], acc[S2][cht][wt][r]);
                        acc[S2][cht][wt] = (f32x4){0.f, 0.f, 0.f, 0.f};
                    }
            }
        }
    };

    using std::integral_constant;
    for (int sb = 0; sb < 30; sb += 6) {
        step(sb + 0, integral_constant<int, 0>{}, integral_constant<int, 0>{});
        step(sb + 1, integral_constant<int, 1>{}, integral_constant<int, 1>{});
        step(sb + 2, integral_constant<int, 2>{}, integral_constant<int, 0>{});
        step(sb + 3, integral_constant<int, 0>{}, integral_constant<int, 1>{});
        step(sb + 4, integral_constant<int, 1>{}, integral_constant<int, 0>{});
        step(sb + 5, integral_constant<int, 2>{}, integral_constant<int, 1>{});
    }
    step(30, integral_constant<int, 0>{}, integral_constant<int, 0>{});
    step(31, integral_constant<int, 1>{}, integral_constant<int, 1>{});

    // bias + softmax over channels (4-lane group: lanes m, m+16, m+32, m+48)
    if (hOK) {
#pragma unroll
        for (int wt = 0; wt < 2; ++wt) {
            float vals[8];
            bool  vld[8];
            float mx = -FLT_MAX;
#pragma unroll
            for (int cht = 0; cht < 2; ++cht)
#pragma unroll
                for (int r = 0; r < 4; ++r) {
                    int c = cht * 16 + 4 * g + r;
                    bool v = (c < 24);
                    float val = -FLT_MAX;
                    if (v) val = mn[cht][wt][r] + bias[c];
                    vals[cht * 4 + r] = val;
                    vld[cht * 4 + r] = v;
                    mx = fmaxf(mx, val);
                }
            mx = fmaxf(mx, __shfl_xor(mx, 16));
            mx = fmaxf(mx, __shfl_xor(mx, 32));
            float sum = 0.f;
#pragma unroll
            for (int j = 0; j < 8; ++j) {
                vals[j] = vld[j] ? expf(vals[j] - mx) : 0.f;
                sum += vals[j];
            }
            sum += __shfl_xor(sum, 16);
            sum += __shfl_xor(sum, 32);
            const float inv = 1.0f / sum;
            const int w = wt * 14 + m;               // wt0: w=0..15; wt1: w=16..29 (m>=2)
            if (wt == 0 || m >= 2) {
#pragma unroll
                for (int cht = 0; cht < 2; ++cht)
#pragma unroll
                    for (int r = 0; r < 4; ++r) {
                        int c = cht * 16 + 4 * g + r;
                        if (c < 24)
                            out[((size_t)(n * 24 + c) * 30 + h) * 30 + w]
                                = vals[cht * 4 + r] * inv;
                    }
            }
        }
    }
}

extern "C" void kernel_launch(void* const* d_in, const int* in_sizes, int n_in,
                              void* d_out, int out_size, void* d_ws, size_t ws_size,
                              hipStream_t stream) {
    const float* x    = (const float*)d_in[0];
    const float* wgt  = (const float*)d_in[1];
    const float* bias = (const float*)d_in[2];
    prep_weights<<<12, 256, 0, stream>>>(wgt, (unsigned*)d_ws);     // 12288 B of d_ws
    conv_mfma<<<N_BATCH * 8, 256, 0, stream>>>(x, (const char*)d_ws, bias, (float*)d_out);
}

// Round 8
// 118.984 us; speedup vs baseline: 4.6026x; 1.0687x over previous
//
#include <hip/hip_runtime.h>
#include <math.h>
#include <float.h>
#include <type_traits>

typedef _Float16 f16x8 __attribute__((ext_vector_type(8)));
typedef float    f32x4 __attribute__((ext_vector_type(4)));

#define N_BATCH 256

static __device__ __forceinline__ f32x4 MM(f16x8 a, f16x8 b, f32x4 c) {
    return __builtin_amdgcn_mfma_f32_16x16x32_f16(a, b, c, 0, 0, 0);
}

// A-fragments (fp16 RTN): set f = kd*2 + cht (6 sets); dword i = f*256 + lane*4 + r.
// Lane l holds A[ch = cht*16 + (l&15)][k = 8*(l>>4) + 2r + half]; k = ci*9+kh*3+kw; k>=27 -> 0.
__global__ void prep_weights(const float* __restrict__ w, unsigned* __restrict__ ws) {
    int i = blockIdx.x * 256 + threadIdx.x;          // 1536 dwords
    if (i >= 1536) return;
    int f = i >> 8, rem = i & 255;
    int lane = rem >> 2, r = rem & 3;
    int kd = f >> 1, cht = f & 1;
    int g = lane >> 4, chl = lane & 15;
    int ch = cht * 16 + chl;
    unsigned outv = 0;
    for (int half = 0; half < 2; ++half) {
        int k = 8 * g + 2 * r + half;
        unsigned short bits = 0;                     // exact zero pad
        if (ch < 24 && k < 27) {
            int ci = k / 9, rr = k % 9, kh = rr / 3, kw = rr % 3;
            union { _Float16 h; unsigned short u; } cv;
            cv.h = (_Float16)w[(((ch * 3 + ci) * 3 + kd) * 3 + kh) * 3 + kw];
            bits = cv.u;
        }
        outv |= (unsigned)bits << (16 * half);
    }
    ws[i] = outv;
}

__global__ __launch_bounds__(64) void conv_mfma(
    const float* __restrict__ x, const char* __restrict__ wsp,
    const float* __restrict__ bias, float* __restrict__ out)
{
    // double-buffered f32 slice: [buf][row 0..8][col 0..31], row-rotated cols
    __shared__ __align__(16) float xs[2 * 288];

    const int lane = threadIdx.x;                    // 0..63
    const int g = lane >> 4, m = lane & 15;
    // XCD-bijective swizzle: 7680 = 8 * 960; h-neighbors share an XCD L2
    const int lb = (blockIdx.x >> 3) + (blockIdx.x & 7) * 960;
    const int n = lb / 30, h = lb - n * 30;          // h in 0..29; rows h..h+2 <= 31

    // ---- staging source (pre-rotated cols so linear global_load_lds lands rotated)
    const int r1  = lane >> 3;                       // LDS row 0..7 (row 8 via call 2)
    const int c4  = (lane & 7) * 4;
    const int ci1 = r1 / 3, dr1 = r1 - ci1 * 3;
    const int sc1 = (c4 - 8 * (r1 & 3)) & 31;        // rot(row)=8*(row&3); blocks of 4 never wrap
    const char* gb1 = (const char*)(x + ((size_t)(n * 3 + ci1) * 32768
                                          + (size_t)(h + dr1) * 32 + sc1));
    const char* gb2 = (const char*)(x + ((size_t)(n * 3 + 2) * 32768
                                          + (size_t)(h + 2) * 32 + lane * 4)); // lanes<8, row 8 rot=0

    // ---- gather byte-offsets (precomputed once; buffer parity is an imm offset)
    int voffb[16];
#pragma unroll
    for (int wt = 0; wt < 2; ++wt)
#pragma unroll
        for (int j = 0; j < 8; ++j) {
            int k = 8 * g + j;
            int row, col;
            if (k < 27) {
                int ci = k / 9, rr = k % 9, kh = rr / 3, kw = rr % 3;
                row = ci * 3 + kh;
                col = (m + wt * 14 + kw + 8 * (row & 3)) & 31;
            } else { row = 0; col = m; }             // finite garbage * A=0 = 0
            voffb[wt * 8 + j] = (row * 32 + col) * 4;
        }

    // ---- preload 6 A-fragments (loop-invariant, 24 VGPRs)
    const char* wl = wsp + (size_t)lane * 16;
    f16x8 aH[3][2];
#pragma unroll
    for (int kd = 0; kd < 3; ++kd)
#pragma unroll
        for (int cht = 0; cht < 2; ++cht)
            aH[kd][cht] = *(const f16x8*)(wl + (size_t)(kd * 2 + cht) * 1024);

    f32x4 acc[3][2][2];                              // [depth%3][cht][wt]
    f32x4 mn[2][2];
#pragma unroll
    for (int a = 0; a < 3; ++a)
#pragma unroll
        for (int b = 0; b < 2; ++b)
#pragma unroll
            for (int c = 0; c < 2; ++c) acc[a][b][c] = (f32x4){0.f, 0.f, 0.f, 0.f};
#pragma unroll
    for (int b = 0; b < 2; ++b)
#pragma unroll
        for (int c = 0; c < 2; ++c) mn[b][c] = (f32x4){FLT_MAX, FLT_MAX, FLT_MAX, FLT_MAX};

    auto stage = [&](int s, int buf) {               // issue 1152B slice load (async)
        __builtin_amdgcn_global_load_lds(
            (const __attribute__((address_space(1))) unsigned*)(gb1 + (size_t)s * 4096),
            (__attribute__((address_space(3))) unsigned*)(xs + buf * 288), 16, 0, 0);
        if (lane < 8)
            __builtin_amdgcn_global_load_lds(
                (const __attribute__((address_space(1))) unsigned*)(gb2 + (size_t)s * 4096),
                (__attribute__((address_space(3))) unsigned*)(xs + buf * 288 + 256), 16, 0, 0);
    };

    const char* xsb = (const char*)xs;

    auto step = [&](int s, auto smc, auto slc, auto k0c, auto k1c, auto k2c) {
        constexpr int  SM = decltype(smc)::value;    // s % 3
        constexpr int  SL = decltype(slc)::value;    // s & 1
        constexpr bool K0 = decltype(k0c)::value;    // s <= 29
        constexpr bool K1 = decltype(k1c)::value;    // 1 <= s <= 30
        constexpr bool K2 = decltype(k2c)::value;    // s >= 2 (and retire depth s-2)

        asm volatile("s_waitcnt vmcnt(0)" ::: "memory");   // slice s resident
        __builtin_amdgcn_sched_barrier(0);
        if (s < 31) stage(s + 1, SL ^ 1);            // prefetch; NOT drained by our wait

#pragma unroll
        for (int wt = 0; wt < 2; ++wt) {
            f16x8 bf;
#pragma unroll
            for (int j = 0; j < 8; ++j)
                bf[j] = (_Float16)(*(const float*)(xsb + SL * 1152 + voffb[wt * 8 + j]));
            if (K0) {
                acc[SM][0][wt] = MM(aH[0][0], bf, acc[SM][0][wt]);
                acc[SM][1][wt] = MM(aH[0][1], bf, acc[SM][1][wt]);
            }
            if (K1) {
                constexpr int S1 = (SM + 2) % 3;
                acc[S1][0][wt] = MM(aH[1][0], bf, acc[S1][0][wt]);
                acc[S1][1][wt] = MM(aH[1][1], bf, acc[S1][1][wt]);
            }
            if (K2) {
                constexpr int S2 = (SM + 1) % 3;
                acc[S2][0][wt] = MM(aH[2][0], bf, acc[S2][0][wt]);
                acc[S2][1][wt] = MM(aH[2][1], bf, acc[S2][1][wt]);
            }
        }
        if (K2) {                                    // retire depth s-2
            constexpr int S2 = (SM + 1) % 3;
#pragma unroll
            for (int cht = 0; cht < 2; ++cht)
#pragma unroll
                for (int wt = 0; wt < 2; ++wt) {
#pragma unroll
                    for (int r = 0; r < 4; ++r)
                        mn[cht][wt][r] = fminf(mn[cht][wt][r], acc[S2][cht][wt][r]);
                    acc[S2][cht][wt] = (f32x4){0.f, 0.f, 0.f, 0.f};
                }
        }
    };

#define STEP(S, SMV, SLV, B0, B1, B2)                                          \
    step(S, std::integral_constant<int, SMV>{}, std::integral_constant<int, SLV>{}, \
         std::integral_constant<bool, B0>{}, std::integral_constant<bool, B1>{},    \
         std::integral_constant<bool, B2>{})

    stage(0, 0);
    STEP(0, 0, 0, true, false, false);
    STEP(1, 1, 1, true, true,  false);
#pragma clang loop unroll(disable)
    for (int it = 0; it < 4; ++it) {
        const int s = 2 + it * 6;
        STEP(s + 0, 2, 0, true, true, true);
        STEP(s + 1, 0, 1, true, true, true);
        STEP(s + 2, 1, 0, true, true, true);
        STEP(s + 3, 2, 1, true, true, true);
        STEP(s + 4, 0, 0, true, true, true);
        STEP(s + 5, 1, 1, true, true, true);
    }
    STEP(26, 2, 0, true, true, true);
    STEP(27, 0, 1, true, true, true);
    STEP(28, 1, 0, true, true, true);
    STEP(29, 2, 1, true, true, true);
    STEP(30, 0, 0, false, true,  true);
    STEP(31, 1, 1, false, false, true);
#undef STEP

    // ---- bias + softmax over channels (lanes m, m+16, m+32, m+48 hold one column)
#pragma unroll
    for (int wt = 0; wt < 2; ++wt) {
        float vals[8];
        float mx = -FLT_MAX;
#pragma unroll
        for (int cht = 0; cht < 2; ++cht)
#pragma unroll
            for (int r = 0; r < 4; ++r) {
                int c  = cht * 16 + 4 * g + r;
                int cc = (c < 24) ? c : 0;           // guard OOB bias load
                float val = mn[cht][wt][r] + bias[cc];
                if (c >= 24) val = -FLT_MAX;
                vals[cht * 4 + r] = val;
                mx = fmaxf(mx, val);
            }
        mx = fmaxf(mx, __shfl_xor(mx, 16));
        mx = fmaxf(mx, __shfl_xor(mx, 32));
        float sum = 0.f;
#pragma unroll
        for (int jj = 0; jj < 8; ++jj) {
            float e = (vals[jj] > -FLT_MAX * 0.5f) ? expf(vals[jj] - mx) : 0.f;
            vals[jj] = e;
            sum += e;
        }
        sum += __shfl_xor(sum, 16);
        sum += __shfl_xor(sum, 32);
        const float inv = 1.0f / sum;
        const int w = wt * 14 + m;                   // wt0: 0..15; wt1: 16..29 (m>=2)
        if (wt == 0 || m >= 2) {
#pragma unroll
            for (int cht = 0; cht < 2; ++cht)
#pragma unroll
                for (int r = 0; r < 4; ++r) {
                    int c = cht * 16 + 4 * g + r;
                    if (c < 24)
                        out[((size_t)(n * 24 + c) * 30 + h) * 30 + w] = vals[cht * 4 + r] * inv;
                }
        }
    }
}

extern "C" void kernel_launch(void* const* d_in, const int* in_sizes, int n_in,
                              void* d_out, int out_size, void* d_ws, size_t ws_size,
                              hipStream_t stream) {
    const float* x    = (const float*)d_in[0];
    const float* wgt  = (const float*)d_in[1];
    const float* bias = (const float*)d_in[2];
    prep_weights<<<6, 256, 0, stream>>>(wgt, (unsigned*)d_ws);      // 6144 B of d_ws
    conv_mfma<<<N_BATCH * 30, 64, 0, stream>>>(x, (const char*)d_ws, bias, (float*)d_out);
}